// Round 12
// baseline (42.586 us; speedup 1.0000x reference)
//
#include <hip/hip_runtime.h>

// Chamfer-style point loss via MFMA 16x16x32 bf16 (layout VERIFIED R5/R9/R11):
// B=16, N=4096, F=3. elem(i,j) = x.y - sqx/2 - sqy/2 = -D/2.
// R12: the 4 waves of a block share one B-stream -> stage the block's whole
// 64KB j-chunk in LDS once (permuted: lane L's fragment at slot L&31 =>
// conflict-free ds_read_b128, upper half-wave broadcasts). Kills the per-wave
// L1 traffic that R9-R11 showed to be the wall.

constexpr int B_ = 16;
constexpr int N_ = 4096;
constexpr int BN = B_ * N_;          // 65536
constexpr int BLK = 256;
constexpr int JSPLIT = 2;
constexpr int JCHUNK = N_ / JSPLIT;  // 2048 points
constexpr int JT2 = JCHUNK / 16;     // 128 j-tiles per block

using bf16x8 = __attribute__((ext_vector_type(8))) __bf16;
using f32x4  = __attribute__((ext_vector_type(4))) float;

__device__ inline uint bf16_rne(float f) {
    uint u = __float_as_uint(f);
    return (u + 0x7FFFu + ((u >> 16) & 1u)) >> 16;
}
__device__ inline float bf16_f(uint h) { return __uint_as_float(h << 16); }

// K-slot packing (16 bf16 = 32B per point, per role) — identical to R5:
// A-row (X): [hx,hy,hz, lx,ly,lz, hx,hy | hz, 1, 1, thx, tlx, 0,0,0]
// B-col (Y): [hx,hy,hz, hx,hy,hz, lx,ly | lz, thy, tly, 1, 1, 0,0,0]
__global__ __launch_bounds__(BLK)
void prep_kernel(const float* __restrict__ a1, const float* __restrict__ a2,
                 uint4* __restrict__ A1, uint4* __restrict__ B1,
                 uint4* __restrict__ A2, uint4* __restrict__ B2) {
    int gi = blockIdx.x * BLK + threadIdx.x;           // [0, BN)
    const float* in = blockIdx.y ? a2 : a1;
    uint4* Ao = blockIdx.y ? A2 : A1;
    uint4* Bo = blockIdx.y ? B2 : B1;
    float x = in[3 * gi], y = in[3 * gi + 1], z = in[3 * gi + 2];
    float sq = fmaf(x, x, fmaf(y, y, z * z));
    float t = -0.5f * sq;
    uint hx = bf16_rne(x), hy = bf16_rne(y), hz = bf16_rne(z);
    uint lx = bf16_rne(x - bf16_f(hx));
    uint ly = bf16_rne(y - bf16_f(hy));
    uint lz = bf16_rne(z - bf16_f(hz));
    uint th = bf16_rne(t);
    uint tl = bf16_rne(t - bf16_f(th));
    const uint ONE = 0x3F80u;
    Ao[2 * gi]     = make_uint4(hx | (hy << 16), hz | (lx << 16), ly | (lz << 16), hx | (hy << 16));
    Ao[2 * gi + 1] = make_uint4(hz | (ONE << 16), ONE | (th << 16), tl, 0u);
    Bo[2 * gi]     = make_uint4(hx | (hy << 16), hz | (hx << 16), hy | (hz << 16), lx | (ly << 16));
    Bo[2 * gi + 1] = make_uint4(lz | (th << 16), tl | (ONE << 16), ONE, 0u);
}

// Two j-tiles folded into all 4 i-tile accumulators: 8 MFMA + 16 max3.
#define FOLDP(Qa, Qb) {                                                          \
    f32x4 oA = __builtin_amdgcn_mfma_f32_16x16x32_bf16(a0, (Qa), cz, 0, 0, 0);   \
    f32x4 oB = __builtin_amdgcn_mfma_f32_16x16x32_bf16(a1, (Qa), cz, 0, 0, 0);   \
    f32x4 oC = __builtin_amdgcn_mfma_f32_16x16x32_bf16(a2, (Qa), cz, 0, 0, 0);   \
    f32x4 oD = __builtin_amdgcn_mfma_f32_16x16x32_bf16(a3, (Qa), cz, 0, 0, 0);   \
    f32x4 oE = __builtin_amdgcn_mfma_f32_16x16x32_bf16(a0, (Qb), cz, 0, 0, 0);   \
    f32x4 oF = __builtin_amdgcn_mfma_f32_16x16x32_bf16(a1, (Qb), cz, 0, 0, 0);   \
    f32x4 oG = __builtin_amdgcn_mfma_f32_16x16x32_bf16(a2, (Qb), cz, 0, 0, 0);   \
    f32x4 oH = __builtin_amdgcn_mfma_f32_16x16x32_bf16(a3, (Qb), cz, 0, 0, 0);   \
    _Pragma("unroll")                                                            \
    for (int r = 0; r < 4; ++r) {                                                \
        vm0[r] = fmaxf(fmaxf(vm0[r], oA[r]), oE[r]);                             \
        vm1[r] = fmaxf(fmaxf(vm1[r], oB[r]), oF[r]);                             \
        vm2[r] = fmaxf(fmaxf(vm2[r], oC[r]), oG[r]);                             \
        vm3[r] = fmaxf(fmaxf(vm3[r], oD[r]), oH[r]);                             \
    } }

// grid: (N/256=16, B=16, 2*JSPLIT=4) = 1024 blocks = 2 resident/CU (64KB LDS).
// Wave: FOUR 16-i tiles (64 i), JCHUNK j's from LDS.
__global__ __launch_bounds__(BLK, 2)
void minmax_kernel(const uint4* __restrict__ A1u, const uint4* __restrict__ B1u,
                   const uint4* __restrict__ A2u, const uint4* __restrict__ B2u,
                   float* __restrict__ vout) {
    __shared__ uint4 smem[JT2 * 32];                   // 64 KB
    int z = blockIdx.z, b = blockIdx.y;
    int d = z >> 1, s = z & 1;
    const bf16x8* __restrict__ Aarr = (const bf16x8*)(d ? A2u : A1u);
    const uint4*  __restrict__ Bu   = (d ? B1u : B2u);
    int tid = threadIdx.x;
    int L = tid & 63, w = tid >> 6;
    int lpt = L & 15;
    bool act = L < 32;                                 // k-groups 2,3 are zero
    int ibase = blockIdx.x * 256 + w * 64;             // i within batch row
    int j0 = s * JCHUNK;

    // Stage 64KB: LDS slot (t*32 + sl) holds B-fragment(point t*16+(sl&15),
    // half sl>>4)  =>  lane L reads slot t*32 + (L&31): 16B-consecutive,
    // conflict-free; lanes 32-63 duplicate (LDS broadcast).
#pragma unroll
    for (int k = 0; k < 16; ++k) {
        int F = k * 256 + tid;
        int t = F >> 5, sl = F & 31;
        smem[F] = Bu[(size_t)(b * N_ + j0 + (t << 4) + (sl & 15)) * 2 + (sl >> 4)];
    }

    const bf16x8* pA = Aarr + (size_t)(b * N_ + ibase + lpt) * 2 + ((L >> 4) & 1);
    uint4 zu; zu.x = zu.y = zu.z = zu.w = 0u;
    bf16x8 zf = __builtin_bit_cast(bf16x8, zu);
    bf16x8 a0 = act ? pA[0] : zf;                      // i-tiles 0..3
    bf16x8 a1 = act ? pA[32] : zf;
    bf16x8 a2 = act ? pA[64] : zf;
    bf16x8 a3 = act ? pA[96] : zf;
    f32x4 cz = {0.f, 0.f, 0.f, 0.f};
    f32x4 vm0 = {-3.0e38f, -3.0e38f, -3.0e38f, -3.0e38f};
    f32x4 vm1 = vm0, vm2 = vm0, vm3 = vm0;

    __syncthreads();

    int lslot = L & 31;
#pragma unroll 2
    for (int t = 0; t < JT2; t += 2) {
        bf16x8 q0 = __builtin_bit_cast(bf16x8, smem[t * 32 + lslot]);
        bf16x8 q1 = __builtin_bit_cast(bf16x8, smem[t * 32 + 32 + lslot]);
        FOLDP(q0, q1)
    }

    // butterfly max across the 16 "col" (j) lanes — verified epilogue
#pragma unroll
    for (int off = 1; off < 16; off <<= 1)
#pragma unroll
        for (int r = 0; r < 4; ++r) {
            vm0[r] = fmaxf(vm0[r], __shfl_xor(vm0[r], off));
            vm1[r] = fmaxf(vm1[r], __shfl_xor(vm1[r], off));
            vm2[r] = fmaxf(vm2[r], __shfl_xor(vm2[r], off));
            vm3[r] = fmaxf(vm3[r], __shfl_xor(vm3[r], off));
        }
    if (lpt == 0) {
        int rg = L >> 4;                               // 0..3
#pragma unroll
        for (int r = 0; r < 4; ++r) {
            int row = rg * 4 + r;                      // 0..15 within tile
            int o = z * BN + b * N_ + ibase + row;
            vout[o] = vm0[r];
            vout[o + 16] = vm1[r];
            vout[o + 32] = vm2[r];
            vout[o + 48] = vm3[r];
        }
    }
}

__device__ inline float block_sum_256(float v, float* red4) {
    for (int off = 32; off; off >>= 1) v += __shfl_down(v, off, 64);
    int lane = threadIdx.x & 63, w = threadIdx.x >> 6;
    if (lane == 0) red4[w] = v;
    __syncthreads();
    return red4[0] + red4[1] + red4[2] + red4[3];
}

// combine j-splits (max), then sum: 256 blocks x 256 threads == BN (R8 path)
__global__ __launch_bounds__(BLK)
void reduce1_kernel(const float* __restrict__ vout, float* __restrict__ sums) {
    int t = blockIdx.x * BLK + threadIdx.x;
    float m0 = fmaxf(vout[t], vout[BN + t]);              // d=0: z=0,1
    float m1 = fmaxf(vout[2 * BN + t], vout[3 * BN + t]); // d=1: z=2,3
    float v = -2.0f * (m0 + m1);
    __shared__ float red4[4];
    float sm = block_sum_256(v, red4);
    if (threadIdx.x == 0) sums[blockIdx.x] = sm;
}

__global__ __launch_bounds__(BLK)
void reduce2_kernel(const float* __restrict__ sums, float* __restrict__ out) {
    float v = sums[threadIdx.x];
    __shared__ float red4[4];
    float sm = block_sum_256(v, red4);
    if (threadIdx.x == 0) out[0] = sm * (50.0f / (float)BN);
}

extern "C" void kernel_launch(void* const* d_in, const int* in_sizes, int n_in,
                              void* d_out, int out_size, void* d_ws, size_t ws_size,
                              hipStream_t stream) {
    const float* a1 = (const float*)d_in[0];
    const float* a2 = (const float*)d_in[1];
    char* ws = (char*)d_ws;
    uint4* A1 = (uint4*)(ws);                          // 2 MB each
    uint4* B1 = (uint4*)(ws + (2u << 20));
    uint4* A2 = (uint4*)(ws + (4u << 20));
    uint4* B2 = (uint4*)(ws + (6u << 20));
    float* vout = (float*)(ws + (8u << 20));           // 4*BN*4 = 1 MB
    float* sums = (float*)(ws + (9u << 20));           // 1 KB
    float* out = (float*)d_out;

    prep_kernel<<<dim3(BN / BLK, 2), BLK, 0, stream>>>(a1, a2, A1, B1, A2, B2);
    minmax_kernel<<<dim3(N_ / 256, B_, 2 * JSPLIT), BLK, 0, stream>>>(A1, B1, A2, B2, vout);
    reduce1_kernel<<<dim3(BN / BLK), BLK, 0, stream>>>(vout, sums);
    reduce2_kernel<<<dim3(1), BLK, 0, stream>>>(sums, out);
}

// Round 13
// 40.890 us; speedup vs baseline: 1.0415x; 1.0415x over previous
//
#include <hip/hip_runtime.h>

// Chamfer-style point loss via MFMA 16x16x32 bf16 (layout VERIFIED R5/R9/R11/R12):
// B=16, N=4096, F=3. elem(i,j) = x.y - sqx/2 - sqy/2 = -D/2.
// R13: MFMA floor is 16.6us PER-CU (4.85 cyc/MFMA per CU, not per SIMD).
// R12's 64KB LDS allowed only 2 blocks/CU = 2 waves/SIMD -> stalls. JSPLIT=4
// (32KB LDS) restores 5 blocks/CU = 5 waves/SIMD on the same verified core.

constexpr int B_ = 16;
constexpr int N_ = 4096;
constexpr int BN = B_ * N_;          // 65536
constexpr int BLK = 256;
constexpr int JSPLIT = 4;
constexpr int JCHUNK = N_ / JSPLIT;  // 1024 points
constexpr int JT4 = JCHUNK / 16;     // 64 j-tiles per block

using bf16x8 = __attribute__((ext_vector_type(8))) __bf16;
using f32x4  = __attribute__((ext_vector_type(4))) float;

__device__ inline uint bf16_rne(float f) {
    uint u = __float_as_uint(f);
    return (u + 0x7FFFu + ((u >> 16) & 1u)) >> 16;
}
__device__ inline float bf16_f(uint h) { return __uint_as_float(h << 16); }

// K-slot packing (16 bf16 = 32B per point, per role) — identical to R5:
// A-row (X): [hx,hy,hz, lx,ly,lz, hx,hy | hz, 1, 1, thx, tlx, 0,0,0]
// B-col (Y): [hx,hy,hz, hx,hy,hz, lx,ly | lz, thy, tly, 1, 1, 0,0,0]
__global__ __launch_bounds__(BLK)
void prep_kernel(const float* __restrict__ a1, const float* __restrict__ a2,
                 uint4* __restrict__ A1, uint4* __restrict__ B1,
                 uint4* __restrict__ A2, uint4* __restrict__ B2) {
    int gi = blockIdx.x * BLK + threadIdx.x;           // [0, BN)
    const float* in = blockIdx.y ? a2 : a1;
    uint4* Ao = blockIdx.y ? A2 : A1;
    uint4* Bo = blockIdx.y ? B2 : B1;
    float x = in[3 * gi], y = in[3 * gi + 1], z = in[3 * gi + 2];
    float sq = fmaf(x, x, fmaf(y, y, z * z));
    float t = -0.5f * sq;
    uint hx = bf16_rne(x), hy = bf16_rne(y), hz = bf16_rne(z);
    uint lx = bf16_rne(x - bf16_f(hx));
    uint ly = bf16_rne(y - bf16_f(hy));
    uint lz = bf16_rne(z - bf16_f(hz));
    uint th = bf16_rne(t);
    uint tl = bf16_rne(t - bf16_f(th));
    const uint ONE = 0x3F80u;
    Ao[2 * gi]     = make_uint4(hx | (hy << 16), hz | (lx << 16), ly | (lz << 16), hx | (hy << 16));
    Ao[2 * gi + 1] = make_uint4(hz | (ONE << 16), ONE | (th << 16), tl, 0u);
    Bo[2 * gi]     = make_uint4(hx | (hy << 16), hz | (hx << 16), hy | (hz << 16), lx | (ly << 16));
    Bo[2 * gi + 1] = make_uint4(lz | (th << 16), tl | (ONE << 16), ONE, 0u);
}

// Two j-tiles folded into all 4 i-tile accumulators: 8 MFMA + 16 max3.
#define FOLDP(Qa, Qb) {                                                          \
    f32x4 oA = __builtin_amdgcn_mfma_f32_16x16x32_bf16(a0, (Qa), cz, 0, 0, 0);   \
    f32x4 oB = __builtin_amdgcn_mfma_f32_16x16x32_bf16(a1, (Qa), cz, 0, 0, 0);   \
    f32x4 oC = __builtin_amdgcn_mfma_f32_16x16x32_bf16(a2, (Qa), cz, 0, 0, 0);   \
    f32x4 oD = __builtin_amdgcn_mfma_f32_16x16x32_bf16(a3, (Qa), cz, 0, 0, 0);   \
    f32x4 oE = __builtin_amdgcn_mfma_f32_16x16x32_bf16(a0, (Qb), cz, 0, 0, 0);   \
    f32x4 oF = __builtin_amdgcn_mfma_f32_16x16x32_bf16(a1, (Qb), cz, 0, 0, 0);   \
    f32x4 oG = __builtin_amdgcn_mfma_f32_16x16x32_bf16(a2, (Qb), cz, 0, 0, 0);   \
    f32x4 oH = __builtin_amdgcn_mfma_f32_16x16x32_bf16(a3, (Qb), cz, 0, 0, 0);   \
    _Pragma("unroll")                                                            \
    for (int r = 0; r < 4; ++r) {                                                \
        vm0[r] = fmaxf(fmaxf(vm0[r], oA[r]), oE[r]);                             \
        vm1[r] = fmaxf(fmaxf(vm1[r], oB[r]), oF[r]);                             \
        vm2[r] = fmaxf(fmaxf(vm2[r], oC[r]), oG[r]);                             \
        vm3[r] = fmaxf(fmaxf(vm3[r], oD[r]), oH[r]);                             \
    } }

// grid: (N/256=16, B=16, 2*JSPLIT=8) = 2048 blocks; 32KB LDS -> 5 resident/CU.
// Wave: FOUR 16-i tiles (64 i), JCHUNK j's from LDS.
__global__ __launch_bounds__(BLK, 4)
void minmax_kernel(const uint4* __restrict__ A1u, const uint4* __restrict__ B1u,
                   const uint4* __restrict__ A2u, const uint4* __restrict__ B2u,
                   float* __restrict__ vout) {
    __shared__ uint4 smem[JT4 * 32];                   // 32 KB
    int z = blockIdx.z, b = blockIdx.y;
    int d = z >> 2, s = z & 3;
    const bf16x8* __restrict__ Aarr = (const bf16x8*)(d ? A2u : A1u);
    const uint4*  __restrict__ Bu   = (d ? B1u : B2u);
    int tid = threadIdx.x;
    int L = tid & 63, w = tid >> 6;
    int lpt = L & 15;
    bool act = L < 32;                                 // k-groups 2,3 are zero
    int ibase = blockIdx.x * 256 + w * 64;             // i within batch row
    int j0 = s * JCHUNK;

    // Stage 32KB: LDS slot (t*32+sl) = B-fragment(point t*16+(sl&15), half sl>>4)
    // Lane L reads slot t*32 + (L&31): conflict-free ds_read_b128 w/ broadcast.
#pragma unroll
    for (int k = 0; k < 8; ++k) {
        int F = k * 256 + tid;
        int t = F >> 5, sl = F & 31;
        smem[F] = Bu[(size_t)(b * N_ + j0 + (t << 4) + (sl & 15)) * 2 + (sl >> 4)];
    }

    const bf16x8* pA = Aarr + (size_t)(b * N_ + ibase + lpt) * 2 + ((L >> 4) & 1);
    uint4 zu; zu.x = zu.y = zu.z = zu.w = 0u;
    bf16x8 zf = __builtin_bit_cast(bf16x8, zu);
    bf16x8 a0 = act ? pA[0] : zf;                      // i-tiles 0..3
    bf16x8 a1 = act ? pA[32] : zf;
    bf16x8 a2 = act ? pA[64] : zf;
    bf16x8 a3 = act ? pA[96] : zf;
    f32x4 cz = {0.f, 0.f, 0.f, 0.f};
    f32x4 vm0 = {-3.0e38f, -3.0e38f, -3.0e38f, -3.0e38f};
    f32x4 vm1 = vm0, vm2 = vm0, vm3 = vm0;

    __syncthreads();

    int lslot = L & 31;
#pragma unroll 2
    for (int t = 0; t < JT4; t += 2) {
        bf16x8 q0 = __builtin_bit_cast(bf16x8, smem[t * 32 + lslot]);
        bf16x8 q1 = __builtin_bit_cast(bf16x8, smem[t * 32 + 32 + lslot]);
        FOLDP(q0, q1)
    }

    // butterfly max across the 16 "col" (j) lanes — verified epilogue
#pragma unroll
    for (int off = 1; off < 16; off <<= 1)
#pragma unroll
        for (int r = 0; r < 4; ++r) {
            vm0[r] = fmaxf(vm0[r], __shfl_xor(vm0[r], off));
            vm1[r] = fmaxf(vm1[r], __shfl_xor(vm1[r], off));
            vm2[r] = fmaxf(vm2[r], __shfl_xor(vm2[r], off));
            vm3[r] = fmaxf(vm3[r], __shfl_xor(vm3[r], off));
        }
    if (lpt == 0) {
        int rg = L >> 4;                               // 0..3
#pragma unroll
        for (int r = 0; r < 4; ++r) {
            int row = rg * 4 + r;                      // 0..15 within tile
            int o = z * BN + b * N_ + ibase + row;
            vout[o] = vm0[r];
            vout[o + 16] = vm1[r];
            vout[o + 32] = vm2[r];
            vout[o + 48] = vm3[r];
        }
    }
}

__device__ inline float block_sum_256(float v, float* red4) {
    for (int off = 32; off; off >>= 1) v += __shfl_down(v, off, 64);
    int lane = threadIdx.x & 63, w = threadIdx.x >> 6;
    if (lane == 0) red4[w] = v;
    __syncthreads();
    return red4[0] + red4[1] + red4[2] + red4[3];
}

// combine 4 j-splits (max) per direction, then sum (R8-verified path)
__global__ __launch_bounds__(BLK)
void reduce1_kernel(const float* __restrict__ vout, float* __restrict__ sums) {
    int t = blockIdx.x * BLK + threadIdx.x;
    float m0 = fmaxf(fmaxf(vout[t], vout[BN + t]),
                     fmaxf(vout[2 * BN + t], vout[3 * BN + t]));       // d=0
    float m1 = fmaxf(fmaxf(vout[4 * BN + t], vout[5 * BN + t]),
                     fmaxf(vout[6 * BN + t], vout[7 * BN + t]));       // d=1
    float v = -2.0f * (m0 + m1);
    __shared__ float red4[4];
    float sm = block_sum_256(v, red4);
    if (threadIdx.x == 0) sums[blockIdx.x] = sm;
}

__global__ __launch_bounds__(BLK)
void reduce2_kernel(const float* __restrict__ sums, float* __restrict__ out) {
    float v = sums[threadIdx.x];
    __shared__ float red4[4];
    float sm = block_sum_256(v, red4);
    if (threadIdx.x == 0) out[0] = sm * (50.0f / (float)BN);
}

extern "C" void kernel_launch(void* const* d_in, const int* in_sizes, int n_in,
                              void* d_out, int out_size, void* d_ws, size_t ws_size,
                              hipStream_t stream) {
    const float* a1 = (const float*)d_in[0];
    const float* a2 = (const float*)d_in[1];
    char* ws = (char*)d_ws;
    uint4* A1 = (uint4*)(ws);                          // 2 MB each
    uint4* B1 = (uint4*)(ws + (2u << 20));
    uint4* A2 = (uint4*)(ws + (4u << 20));
    uint4* B2 = (uint4*)(ws + (6u << 20));
    float* vout = (float*)(ws + (8u << 20));           // 8*BN*4 = 2 MB
    float* sums = (float*)(ws + (10u << 20));          // 1 KB
    float* out = (float*)d_out;

    prep_kernel<<<dim3(BN / BLK, 2), BLK, 0, stream>>>(a1, a2, A1, B1, A2, B2);
    minmax_kernel<<<dim3(N_ / 256, B_, 2 * JSPLIT), BLK, 0, stream>>>(A1, B1, A2, B2, vout);
    reduce1_kernel<<<dim3(BN / BLK), BLK, 0, stream>>>(vout, sums);
    reduce2_kernel<<<dim3(1), BLK, 0, stream>>>(sums, out);
}